// Round 1
// baseline (447.481 us; speedup 1.0000x reference)
//
#include <hip/hip_runtime.h>

#define DD   64      // channels
#define SSTR 72      // LDS self/mean tile row stride (bf16 elems): 2-way only
#define BSH  9       // 512 nodes per bucket
#define BNODES 512
#define BCAPSH 13    // 8192 edges capacity per bucket (mean 6400 + 22 sigma)

typedef unsigned int uint32;
typedef __attribute__((ext_vector_type(8))) short short8;   // 8 bf16 (4 VGPRs)
typedef __attribute__((ext_vector_type(4))) float f32x4;    // MFMA accumulator

__device__ __forceinline__ unsigned short f2bf_rne(float f) {
    uint32 u = __float_as_uint(f);
    u += 0x7fffu + ((u >> 16) & 1u);   // round-to-nearest-even
    return (unsigned short)(u >> 16);
}
__device__ __forceinline__ float bf_lo(uint32 w) { return __uint_as_float(w << 16); }
__device__ __forceinline__ float bf_hi(uint32 w) { return __uint_as_float(w & 0xffff0000u); }
__device__ __forceinline__ float bf2f(unsigned short s) {
    return __uint_as_float(((uint32)s) << 16);
}

// ===========================================================================
// x (fp32) -> bf16 shadow; block 0 zeroes bucket counters; first 96 blocks
// also build the bf16 W^T tables for all 3 layers (wtg[layer][c*128+k],
// k<64 = Wl, k>=64 = Wr) so sage_layer needn't stage W in LDS.
// ===========================================================================
__global__ __launch_bounds__(256) void cvt_kernel(
    const float* __restrict__ x, unsigned short* __restrict__ xb, int n4,
    int* __restrict__ gCnt,
    const float* __restrict__ Wl0, const float* __restrict__ Wr0,
    const float* __restrict__ Wl1, const float* __restrict__ Wr1,
    const float* __restrict__ Wl2, const float* __restrict__ Wr2,
    unsigned short* __restrict__ wtg) {
    const int gid = blockIdx.x * 256 + threadIdx.x;
    if (blockIdx.x == 0) gCnt[threadIdx.x] = 0;
    if (gid < 3 * 2 * DD * DD) {              // 24576 W^T elements
        int layer = gid >> 13;
        int idx   = gid & 8191;
        int k = idx >> 6, c = idx & 63;
        const float* Wsrc;
        if (layer == 0)      Wsrc = (k < DD) ? Wl0 : Wr0;
        else if (layer == 1) Wsrc = (k < DD) ? Wl1 : Wr1;
        else                 Wsrc = (k < DD) ? Wl2 : Wr2;
        float v = Wsrc[(k & (DD - 1)) * DD + c];
        wtg[layer * 8192 + c * 128 + k] = f2bf_rne(v);
    }
    if (gid < n4) {
        float4 v = ((const float4*)x)[gid];
        ushort4 p;
        p.x = f2bf_rne(v.x); p.y = f2bf_rne(v.y);
        p.z = f2bf_rne(v.z); p.w = f2bf_rne(v.w);
        ((ushort4*)xb)[gid] = p;
    }
}

// ===========================================================================
// Pass 1: bucket edges by dst>>9 (LDS histogram, one global atomic per
// (block,bucket), scatter (src,dst) into fixed-capacity bucket regions).
// ===========================================================================
__global__ __launch_bounds__(1024) void bucket_kernel(const int* __restrict__ src,
                                                      const int* __restrict__ dst,
                                                      int* __restrict__ gCnt,
                                                      int2* __restrict__ buf, int E) {
    __shared__ int ldsCnt[256];
    __shared__ int base[256];
    const int t = threadIdx.x;
    if (t < 256) ldsCnt[t] = 0;
    __syncthreads();

    const int e0 = blockIdx.x * 4096;
    int bk[4], rk[4], sv[4], dv[4];
#pragma unroll
    for (int k = 0; k < 4; ++k) {
        int e = e0 + k * 1024 + t;
        bk[k] = -1;
        if (e < E) {
            dv[k] = dst[e];
            sv[k] = src[e];
            bk[k] = dv[k] >> BSH;
            rk[k] = atomicAdd(&ldsCnt[bk[k]], 1);
        }
    }
    __syncthreads();
    if (t < 256 && ldsCnt[t] > 0) base[t] = atomicAdd(&gCnt[t], ldsCnt[t]);
    __syncthreads();
#pragma unroll
    for (int k = 0; k < 4; ++k) {
        if (bk[k] >= 0) {
            int pos = (bk[k] << BCAPSH) + base[bk[k]] + rk[k];
            buf[pos] = make_int2(sv[k], dv[k]);
        }
    }
}

// ===========================================================================
// Pass 2: one block per bucket. Bucket base = masked wave reduction over
// gCnt (one scalar per block, no 256-scan). Degree scan = __shfl_up wave
// scans + 8-entry cross-wave combine. 4 barriers total (was ~36).
// ===========================================================================
__global__ __launch_bounds__(512) void csr_build(const int2* __restrict__ buf,
                                                 const int* __restrict__ gCnt,
                                                 int* __restrict__ offsets,
                                                 int* __restrict__ csr, int N, int E) {
    __shared__ int c1[BNODES];
    __shared__ int s2[BNODES];
    __shared__ int sw[16];
    const int b = blockIdx.x;
    const int t = threadIdx.x;
    const int lane = t & 63;
    const int w = t >> 6;

    // base = sum_{i<b} gCnt[i]  via masked butterfly reduction
    int gv = (t < 256 && t < b) ? gCnt[t] : 0;
#pragma unroll
    for (int d = 1; d < 64; d <<= 1) gv += __shfl_xor(gv, d, 64);
    if (lane == 0) sw[w] = gv;        // waves 4..7 contribute 0
    c1[t] = 0;
    __syncthreads();
    int base = 0;
#pragma unroll
    for (int i = 0; i < 8; ++i) base += sw[i];

    const int cnt = gCnt[b];
    const int2* bb = buf + ((size_t)b << BCAPSH);
    for (int i = t; i < cnt; i += 512) atomicAdd(&c1[bb[i].y & (BNODES - 1)], 1);
    __syncthreads();

    // inclusive scan of the 512 per-node counts: wave scan + cross-wave
    int v = c1[t];
    int x = v;
#pragma unroll
    for (int d = 1; d < 64; d <<= 1) {
        int y = __shfl_up(x, d, 64);
        if (lane >= d) x += y;
    }
    if (lane == 63) sw[8 + w] = x;
    __syncthreads();
    int woff = 0;
    for (int i = 0; i < w; ++i) woff += sw[8 + i];
    int excl = x + woff - v;

    const int node = (b << BSH) + t;
    if (node < N) offsets[node] = base + excl;
    if (b == 0 && t == 0) offsets[N] = E;

    s2[t] = excl;
    c1[t] = 0;
    __syncthreads();

    for (int i = t; i < cnt; i += 512) {
        int2 e = bb[i];
        int d = e.y & (BNODES - 1);
        int r = atomicAdd(&c1[d], 1);
        csr[base + s2[d] + r] = e.x;
    }
}

// ===========================================================================
// Fused SAGE layer (all-bf16 inter-layer state):
//   phase 1: stage self tile (LDS), gather neighbor means (8 lanes/node,
//            8-deep batches) -> LDS mean tile
//   phase 2: MFMA 16x16x32 [mean||self] @ [Wl;Wr] + bl, fp32 accum;
//            B-fragments come straight from the precomputed global bf16 W^T
//            (16 KB, L1-resident, shared by all blocks) -- no LDS staging.
//   MODE 0: hbout = bf16(relu(LN(y)) + self);  MODE 1: out = l2norm(y + self)
// Block = 256 thr = 4 waves = 64 dst nodes. C/D: col=lane&15, row=quad*4+reg.
// LDS = 19.2 KB -> 8 blocks/CU (32 waves/CU, was 4 blocks / 16 waves with
// W^T in LDS); grid 1563 <= 2048 resident -> single scheduling round.
// ===========================================================================
template <int MODE>
__global__ __launch_bounds__(256, 8) void sage_layer(
    const unsigned short* __restrict__ hbin,  // [N,64] bf16 layer input
    const int* __restrict__ offsets,          // [N+1]
    const int* __restrict__ csr,              // [E]
    const unsigned short* __restrict__ wt,    // [64][128] bf16 W^T this layer
    const float* __restrict__ bl,             // [64]
    const float* __restrict__ g,              // [64] LN gamma (MODE 0)
    const float* __restrict__ bta,            // [64] LN beta  (MODE 0)
    unsigned short* __restrict__ hbout,       // [N,64] bf16 (MODE 0)
    float* __restrict__ out,                  // [N,64] fp32 (MODE 1)
    int N) {
    __shared__ unsigned short sSelf[64 * SSTR]; // self rows bf16
    __shared__ unsigned short sMean[64 * SSTR]; // gathered means bf16
    __shared__ float sbl[DD], sg[DD], sb[DD];

    const int t = threadIdx.x;
    const int nbase = blockIdx.x * 64;

    if (t < DD) {
        sbl[t] = bl[t];
        if (MODE == 0) { sg[t] = g[t]; sb[t] = bta[t]; }
    }

    // ---- stage self tile: 64 rows x 8 uint4 chunks, coalesced
#pragma unroll
    for (int r = 0; r < 2; ++r) {
        int idx = r * 256 + t;
        int row = idx >> 3;
        int qq  = idx & 7;
        int n   = min(nbase + row, N - 1);
        uint4 v = ((const uint4*)(hbin + (size_t)n * DD))[qq];
        *(uint4*)(&sSelf[row * SSTR + qq * 8]) = v;
    }

    // ---- gather neighbor means: 32 groups x 8 lanes; 2 nodes per group
    {
        const int grp = t >> 3;
        const int q   = t & 7;           // 16 B chunk within 128 B row
#pragma unroll 1
        for (int rep = 0; rep < 2; ++rep) {
            int local = grp + rep * 32;
            int node  = nbase + local;
            float a0 = 0.f, a1 = 0.f, a2 = 0.f, a3 = 0.f,
                  a4 = 0.f, a5 = 0.f, a6 = 0.f, a7 = 0.f;
            int deg = 0;
            if (node < N) {
                int off0 = offsets[node];
                int off1 = offsets[node + 1];
                deg = off1 - off0;
                for (int j = off0; j < off1; j += 8) {
                    uint4 v[8];
#pragma unroll
                    for (int s = 0; s < 8; ++s) {
                        uint4 tt = make_uint4(0u, 0u, 0u, 0u);
                        int idx = j + s;
                        if (idx < off1) {
                            int sn = __builtin_nontemporal_load(&csr[idx]);
                            tt = ((const uint4*)(hbin + (size_t)sn * DD))[q];
                        }
                        v[s] = tt;
                    }
#pragma unroll
                    for (int s = 0; s < 8; ++s) {
                        a0 += bf_lo(v[s].x); a1 += bf_hi(v[s].x);
                        a2 += bf_lo(v[s].y); a3 += bf_hi(v[s].y);
                        a4 += bf_lo(v[s].z); a5 += bf_hi(v[s].z);
                        a6 += bf_lo(v[s].w); a7 += bf_hi(v[s].w);
                    }
                }
            }
            float invd = 1.0f / fmaxf((float)deg, 1.0f);
            ushort4 pa, pb;
            pa.x = f2bf_rne(a0 * invd); pa.y = f2bf_rne(a1 * invd);
            pa.z = f2bf_rne(a2 * invd); pa.w = f2bf_rne(a3 * invd);
            pb.x = f2bf_rne(a4 * invd); pb.y = f2bf_rne(a5 * invd);
            pb.z = f2bf_rne(a6 * invd); pb.w = f2bf_rne(a7 * invd);
            *(ushort4*)(&sMean[local * SSTR + q * 8])     = pa;
            *(ushort4*)(&sMean[local * SSTR + q * 8 + 4]) = pb;
        }
    }
    __syncthreads();

    // ---- MFMA phase: wave = 16 nodes x 64 cols
    const int wave = t >> 6;
    const int lane = t & 63;
    const int quad = lane >> 4;
    const int n16  = lane & 15;
    const int lbase = wave * 16;

    short8 af[4];
    af[0] = *(const short8*)(&sMean[(lbase + n16) * SSTR + quad * 8]);
    af[1] = *(const short8*)(&sMean[(lbase + n16) * SSTR + 32 + quad * 8]);
    af[2] = *(const short8*)(&sSelf[(lbase + n16) * SSTR + quad * 8]);
    af[3] = *(const short8*)(&sSelf[(lbase + n16) * SSTR + 32 + quad * 8]);

    f32x4 acc[4];
#pragma unroll
    for (int j = 0; j < 4; ++j) {
        float bv = sbl[j * 16 + n16];
        acc[j] = (f32x4){bv, bv, bv, bv};
    }
#pragma unroll
    for (int s = 0; s < 4; ++s) {
#pragma unroll
        for (int j = 0; j < 4; ++j) {
            short8 bf = *(const short8*)(wt + (j * 16 + n16) * 128 + s * 32 + quad * 8);
            acc[j] = __builtin_amdgcn_mfma_f32_16x16x32_bf16(af[s], bf, acc[j], 0, 0, 0);
        }
    }

    // ---- epilogue; residual from the LDS self tile (bf16)
#pragma unroll
    for (int i = 0; i < 4; ++i) {
        const int lrow = lbase + quad * 4 + i;
        const int rr   = nbase + lrow;
        float res[4];
#pragma unroll
        for (int j = 0; j < 4; ++j)
            res[j] = bf2f(sSelf[lrow * SSTR + j * 16 + n16]);
        float o[4];
        if (MODE == 0) {
            float s4 = acc[0][i] + acc[1][i] + acc[2][i] + acc[3][i];
            s4 += __shfl_xor(s4, 1, 64);
            s4 += __shfl_xor(s4, 2, 64);
            s4 += __shfl_xor(s4, 4, 64);
            s4 += __shfl_xor(s4, 8, 64);
            float mu = s4 * (1.0f / 64.0f);
            float d0 = acc[0][i] - mu, d1 = acc[1][i] - mu,
                  d2 = acc[2][i] - mu, d3 = acc[3][i] - mu;
            float qq = d0 * d0 + d1 * d1 + d2 * d2 + d3 * d3;
            qq += __shfl_xor(qq, 1, 64);
            qq += __shfl_xor(qq, 2, 64);
            qq += __shfl_xor(qq, 4, 64);
            qq += __shfl_xor(qq, 8, 64);
            float rstd = rsqrtf(qq * (1.0f / 64.0f) + 1e-5f);
            o[0] = fmaxf(d0 * rstd * sg[ 0 + n16] + sb[ 0 + n16], 0.f) + res[0];
            o[1] = fmaxf(d1 * rstd * sg[16 + n16] + sb[16 + n16], 0.f) + res[1];
            o[2] = fmaxf(d2 * rstd * sg[32 + n16] + sb[32 + n16], 0.f) + res[2];
            o[3] = fmaxf(d3 * rstd * sg[48 + n16] + sb[48 + n16], 0.f) + res[3];
        } else {
            o[0] = acc[0][i] + res[0];
            o[1] = acc[1][i] + res[1];
            o[2] = acc[2][i] + res[2];
            o[3] = acc[3][i] + res[3];
            float qq = o[0] * o[0] + o[1] * o[1] + o[2] * o[2] + o[3] * o[3];
            qq += __shfl_xor(qq, 1, 64);
            qq += __shfl_xor(qq, 2, 64);
            qq += __shfl_xor(qq, 4, 64);
            qq += __shfl_xor(qq, 8, 64);
            float inv = 1.0f / fmaxf(sqrtf(qq), 1e-12f);
            o[0] *= inv; o[1] *= inv; o[2] *= inv; o[3] *= inv;
        }
        if (rr < N) {
#pragma unroll
            for (int j = 0; j < 4; ++j) {
                if (MODE == 0)
                    hbout[(size_t)rr * DD + j * 16 + n16] = f2bf_rne(o[j]);
                else
                    out[(size_t)rr * DD + j * 16 + n16] = o[j];
            }
        }
    }
}

// ===========================================================================
extern "C" void kernel_launch(void* const* d_in, const int* in_sizes, int n_in,
                              void* d_out, int out_size, void* d_ws, size_t ws_size,
                              hipStream_t stream) {
    const float* x   = (const float*)d_in[0];
    const int*   ei  = (const int*)d_in[1];   // [2, E] int32: row0 = src, row1 = dst
    const float* Wl0 = (const float*)d_in[2];
    const float* bl0 = (const float*)d_in[3];
    const float* Wr0 = (const float*)d_in[4];
    const float* Wl1 = (const float*)d_in[5];
    const float* bl1 = (const float*)d_in[6];
    const float* Wr1 = (const float*)d_in[7];
    const float* Wl2 = (const float*)d_in[8];
    const float* bl2 = (const float*)d_in[9];
    const float* Wr2 = (const float*)d_in[10];
    const float* g0  = (const float*)d_in[11];
    const float* b0  = (const float*)d_in[12];
    const float* g1  = (const float*)d_in[13];
    const float* b1  = (const float*)d_in[14];

    const int N = in_sizes[0] / DD;   // 100000
    const int E = in_sizes[1] / 2;    // 1250000
    const int* src = ei;
    const int* dst = ei + E;
    const int NB = (N + BNODES - 1) >> BSH;   // 196 buckets

    // Workspace: bucketBuf int2[256<<13] | HB0, HB1 bf16[N*64] | csr[E] |
    //            offsets[N+1] | gCnt[256] | wtg bf16[3*8192]  (~45.7 MB)
    int2* bucketBuf = (int2*)d_ws;
    unsigned short* HB0 = (unsigned short*)(bucketBuf + ((size_t)256 << BCAPSH));
    unsigned short* HB1 = HB0 + (size_t)N * DD;
    int*   csr     = (int*)(HB1 + (size_t)N * DD);
    int*   offsets = csr + E;
    int*   gCnt    = offsets + (N + 1);
    unsigned short* wtg =
        (unsigned short*)(((size_t)(gCnt + 256) + 15) & ~(size_t)15);
    float* out     = (float*)d_out;

    const int tiles = (N + 63) / 64;
    const int n4    = N * DD / 4;
    const int cgrid = (n4 + 255) / 256;
    const int bgrid = (E + 4095) / 4096;

    // ---- CSR build: bucket counting sort (graph static across layers)
    cvt_kernel<<<cgrid, 256, 0, stream>>>(x, HB0, n4, gCnt,
                                          Wl0, Wr0, Wl1, Wr1, Wl2, Wr2, wtg);
    bucket_kernel<<<bgrid, 1024, 0, stream>>>(src, dst, gCnt, bucketBuf, E);
    csr_build<<<NB, 512, 0, stream>>>(bucketBuf, gCnt, offsets, csr, N, E);

    // ---- 3 fused layers (bf16 ping-pong)
    sage_layer<0><<<tiles, 256, 0, stream>>>(HB0, offsets, csr, wtg,
                                             bl0, g0, b0, HB1, nullptr, N);
    sage_layer<0><<<tiles, 256, 0, stream>>>(HB1, offsets, csr, wtg + 8192,
                                             bl1, g1, b1, HB0, nullptr, N);
    sage_layer<1><<<tiles, 256, 0, stream>>>(HB0, offsets, csr, wtg + 16384,
                                             bl2, nullptr, nullptr, nullptr, out, N);
}

// Round 2
// 411.379 us; speedup vs baseline: 1.0878x; 1.0878x over previous
//
#include <hip/hip_runtime.h>

#define DD   64      // channels
#define SSTR 72      // LDS self/mean tile row stride (bf16 elems): 2-way only
#define BSH  9       // 512 nodes per bucket
#define BNODES 512
#define BCAPSH 13    // 8192 edges capacity per bucket (mean 6400 + 22 sigma)

typedef unsigned int uint32;
typedef __attribute__((ext_vector_type(8))) short short8;   // 8 bf16 (4 VGPRs)
typedef __attribute__((ext_vector_type(4))) float f32x4;    // MFMA accumulator

__device__ __forceinline__ unsigned short f2bf_rne(float f) {
    uint32 u = __float_as_uint(f);
    u += 0x7fffu + ((u >> 16) & 1u);   // round-to-nearest-even
    return (unsigned short)(u >> 16);
}
__device__ __forceinline__ float bf_lo(uint32 w) { return __uint_as_float(w << 16); }
__device__ __forceinline__ float bf_hi(uint32 w) { return __uint_as_float(w & 0xffff0000u); }
__device__ __forceinline__ float bf2f(unsigned short s) {
    return __uint_as_float(((uint32)s) << 16);
}

// ===========================================================================
// x (fp32) -> bf16 shadow; block 0 zeroes bucket counters; first 96 blocks
// also build the bf16 W^T tables for all 3 layers (wtg[layer][c*128+k],
// k<64 = Wl, k>=64 = Wr) so sage_layer needn't stage W in LDS.
// ===========================================================================
__global__ __launch_bounds__(256) void cvt_kernel(
    const float* __restrict__ x, unsigned short* __restrict__ xb, int n4,
    int* __restrict__ gCnt,
    const float* __restrict__ Wl0, const float* __restrict__ Wr0,
    const float* __restrict__ Wl1, const float* __restrict__ Wr1,
    const float* __restrict__ Wl2, const float* __restrict__ Wr2,
    unsigned short* __restrict__ wtg) {
    const int gid = blockIdx.x * 256 + threadIdx.x;
    if (blockIdx.x == 0) gCnt[threadIdx.x] = 0;
    if (gid < 3 * 2 * DD * DD) {              // 24576 W^T elements
        int layer = gid >> 13;
        int idx   = gid & 8191;
        int k = idx >> 6, c = idx & 63;
        const float* Wsrc;
        if (layer == 0)      Wsrc = (k < DD) ? Wl0 : Wr0;
        else if (layer == 1) Wsrc = (k < DD) ? Wl1 : Wr1;
        else                 Wsrc = (k < DD) ? Wl2 : Wr2;
        float v = Wsrc[(k & (DD - 1)) * DD + c];
        wtg[layer * 8192 + c * 128 + k] = f2bf_rne(v);
    }
    if (gid < n4) {
        float4 v = ((const float4*)x)[gid];
        ushort4 p;
        p.x = f2bf_rne(v.x); p.y = f2bf_rne(v.y);
        p.z = f2bf_rne(v.z); p.w = f2bf_rne(v.w);
        ((ushort4*)xb)[gid] = p;
    }
}

// ===========================================================================
// Pass 1: bucket edges by dst>>9 (LDS histogram, one global atomic per
// (block,bucket), scatter (src,dst) into fixed-capacity bucket regions).
// ===========================================================================
__global__ __launch_bounds__(1024) void bucket_kernel(const int* __restrict__ src,
                                                      const int* __restrict__ dst,
                                                      int* __restrict__ gCnt,
                                                      int2* __restrict__ buf, int E) {
    __shared__ int ldsCnt[256];
    __shared__ int base[256];
    const int t = threadIdx.x;
    if (t < 256) ldsCnt[t] = 0;
    __syncthreads();

    const int e0 = blockIdx.x * 4096;
    int bk[4], rk[4], sv[4], dv[4];
#pragma unroll
    for (int k = 0; k < 4; ++k) {
        int e = e0 + k * 1024 + t;
        bk[k] = -1;
        if (e < E) {
            dv[k] = dst[e];
            sv[k] = src[e];
            bk[k] = dv[k] >> BSH;
            rk[k] = atomicAdd(&ldsCnt[bk[k]], 1);
        }
    }
    __syncthreads();
    if (t < 256 && ldsCnt[t] > 0) base[t] = atomicAdd(&gCnt[t], ldsCnt[t]);
    __syncthreads();
#pragma unroll
    for (int k = 0; k < 4; ++k) {
        if (bk[k] >= 0) {
            int pos = (bk[k] << BCAPSH) + base[bk[k]] + rk[k];
            buf[pos] = make_int2(sv[k], dv[k]);
        }
    }
}

// ===========================================================================
// Pass 2: one block per bucket. Bucket base = masked wave reduction over
// gCnt (one scalar per block, no 256-scan). Degree scan = __shfl_up wave
// scans + 8-entry cross-wave combine. 4 barriers total (was ~36).
// ===========================================================================
__global__ __launch_bounds__(512) void csr_build(const int2* __restrict__ buf,
                                                 const int* __restrict__ gCnt,
                                                 int* __restrict__ offsets,
                                                 int* __restrict__ csr, int N, int E) {
    __shared__ int c1[BNODES];
    __shared__ int s2[BNODES];
    __shared__ int sw[16];
    const int b = blockIdx.x;
    const int t = threadIdx.x;
    const int lane = t & 63;
    const int w = t >> 6;

    // base = sum_{i<b} gCnt[i]  via masked butterfly reduction
    int gv = (t < 256 && t < b) ? gCnt[t] : 0;
#pragma unroll
    for (int d = 1; d < 64; d <<= 1) gv += __shfl_xor(gv, d, 64);
    if (lane == 0) sw[w] = gv;        // waves 4..7 contribute 0
    c1[t] = 0;
    __syncthreads();
    int base = 0;
#pragma unroll
    for (int i = 0; i < 8; ++i) base += sw[i];

    const int cnt = gCnt[b];
    const int2* bb = buf + ((size_t)b << BCAPSH);
    for (int i = t; i < cnt; i += 512) atomicAdd(&c1[bb[i].y & (BNODES - 1)], 1);
    __syncthreads();

    // inclusive scan of the 512 per-node counts: wave scan + cross-wave
    int v = c1[t];
    int x = v;
#pragma unroll
    for (int d = 1; d < 64; d <<= 1) {
        int y = __shfl_up(x, d, 64);
        if (lane >= d) x += y;
    }
    if (lane == 63) sw[8 + w] = x;
    __syncthreads();
    int woff = 0;
    for (int i = 0; i < w; ++i) woff += sw[8 + i];
    int excl = x + woff - v;

    const int node = (b << BSH) + t;
    if (node < N) offsets[node] = base + excl;
    if (b == 0 && t == 0) offsets[N] = E;

    s2[t] = excl;
    c1[t] = 0;
    __syncthreads();

    for (int i = t; i < cnt; i += 512) {
        int2 e = bb[i];
        int d = e.y & (BNODES - 1);
        int r = atomicAdd(&c1[d], 1);
        csr[base + s2[d] + r] = e.x;
    }
}

// ===========================================================================
// Fused SAGE layer (all-bf16 inter-layer state):
//   phase 1: stage self tile (LDS), gather neighbor means (8 lanes/node,
//            8-deep batches) -> LDS mean tile
//   phase 2: MFMA 16x16x32 [mean||self] @ [Wl;Wr] + bl, fp32 accum;
//            B-fragments come straight from the precomputed global bf16 W^T
//            (16 KB, L2-resident, shared by all blocks) -- no LDS staging.
//            K-loop is unroll-1 so only 4 W fragments are in flight (16
//            VGPRs) -- full hoist (64 VGPRs) is what spilled at bound 8.
//   MODE 0: hbout = bf16(relu(LN(y)) + self);  MODE 1: out = l2norm(y + self)
// Block = 256 thr = 4 waves = 64 dst nodes. C/D: col=lane&15, row=quad*4+reg.
// LDS = 19.2 KB; __launch_bounds__(256,6): VGPR cap ~85 (gather needs ~55,
// no scratch -- bound 8's 64-cap spilled, tripling HBM traffic), 6 blocks/CU
// = 24 waves/CU, LDS 6x19.5 = 117 KB < 160 KB.
// ===========================================================================
template <int MODE>
__global__ __launch_bounds__(256, 6) void sage_layer(
    const unsigned short* __restrict__ hbin,  // [N,64] bf16 layer input
    const int* __restrict__ offsets,          // [N+1]
    const int* __restrict__ csr,              // [E]
    const unsigned short* __restrict__ wt,    // [64][128] bf16 W^T this layer
    const float* __restrict__ bl,             // [64]
    const float* __restrict__ g,              // [64] LN gamma (MODE 0)
    const float* __restrict__ bta,            // [64] LN beta  (MODE 0)
    unsigned short* __restrict__ hbout,       // [N,64] bf16 (MODE 0)
    float* __restrict__ out,                  // [N,64] fp32 (MODE 1)
    int N) {
    __shared__ unsigned short sSelf[64 * SSTR]; // self rows bf16
    __shared__ unsigned short sMean[64 * SSTR]; // gathered means bf16
    __shared__ float sbl[DD], sg[DD], sb[DD];

    const int t = threadIdx.x;
    const int nbase = blockIdx.x * 64;

    if (t < DD) {
        sbl[t] = bl[t];
        if (MODE == 0) { sg[t] = g[t]; sb[t] = bta[t]; }
    }

    // ---- stage self tile: 64 rows x 8 uint4 chunks, coalesced
#pragma unroll
    for (int r = 0; r < 2; ++r) {
        int idx = r * 256 + t;
        int row = idx >> 3;
        int qq  = idx & 7;
        int n   = min(nbase + row, N - 1);
        uint4 v = ((const uint4*)(hbin + (size_t)n * DD))[qq];
        *(uint4*)(&sSelf[row * SSTR + qq * 8]) = v;
    }

    // ---- gather neighbor means: 32 groups x 8 lanes; 2 nodes per group
    {
        const int grp = t >> 3;
        const int q   = t & 7;           // 16 B chunk within 128 B row
#pragma unroll 1
        for (int rep = 0; rep < 2; ++rep) {
            int local = grp + rep * 32;
            int node  = nbase + local;
            float a0 = 0.f, a1 = 0.f, a2 = 0.f, a3 = 0.f,
                  a4 = 0.f, a5 = 0.f, a6 = 0.f, a7 = 0.f;
            int deg = 0;
            if (node < N) {
                int off0 = offsets[node];
                int off1 = offsets[node + 1];
                deg = off1 - off0;
                for (int j = off0; j < off1; j += 8) {
                    uint4 v[8];
#pragma unroll
                    for (int s = 0; s < 8; ++s) {
                        uint4 tt = make_uint4(0u, 0u, 0u, 0u);
                        int idx = j + s;
                        if (idx < off1) {
                            int sn = __builtin_nontemporal_load(&csr[idx]);
                            tt = ((const uint4*)(hbin + (size_t)sn * DD))[q];
                        }
                        v[s] = tt;
                    }
#pragma unroll
                    for (int s = 0; s < 8; ++s) {
                        a0 += bf_lo(v[s].x); a1 += bf_hi(v[s].x);
                        a2 += bf_lo(v[s].y); a3 += bf_hi(v[s].y);
                        a4 += bf_lo(v[s].z); a5 += bf_hi(v[s].z);
                        a6 += bf_lo(v[s].w); a7 += bf_hi(v[s].w);
                    }
                }
            }
            float invd = 1.0f / fmaxf((float)deg, 1.0f);
            ushort4 pa, pb;
            pa.x = f2bf_rne(a0 * invd); pa.y = f2bf_rne(a1 * invd);
            pa.z = f2bf_rne(a2 * invd); pa.w = f2bf_rne(a3 * invd);
            pb.x = f2bf_rne(a4 * invd); pb.y = f2bf_rne(a5 * invd);
            pb.z = f2bf_rne(a6 * invd); pb.w = f2bf_rne(a7 * invd);
            *(ushort4*)(&sMean[local * SSTR + q * 8])     = pa;
            *(ushort4*)(&sMean[local * SSTR + q * 8 + 4]) = pb;
        }
    }
    __syncthreads();

    // ---- MFMA phase: wave = 16 nodes x 64 cols
    const int wave = t >> 6;
    const int lane = t & 63;
    const int quad = lane >> 4;
    const int n16  = lane & 15;
    const int lbase = wave * 16;

    short8 af[4];
    af[0] = *(const short8*)(&sMean[(lbase + n16) * SSTR + quad * 8]);
    af[1] = *(const short8*)(&sMean[(lbase + n16) * SSTR + 32 + quad * 8]);
    af[2] = *(const short8*)(&sSelf[(lbase + n16) * SSTR + quad * 8]);
    af[3] = *(const short8*)(&sSelf[(lbase + n16) * SSTR + 32 + quad * 8]);

    f32x4 acc[4];
#pragma unroll
    for (int j = 0; j < 4; ++j) {
        float bv = sbl[j * 16 + n16];
        acc[j] = (f32x4){bv, bv, bv, bv};
    }
#pragma unroll 1
    for (int s = 0; s < 4; ++s) {
#pragma unroll
        for (int j = 0; j < 4; ++j) {
            short8 bf = *(const short8*)(wt + (j * 16 + n16) * 128 + s * 32 + quad * 8);
            acc[j] = __builtin_amdgcn_mfma_f32_16x16x32_bf16(af[s], bf, acc[j], 0, 0, 0);
        }
    }

    // ---- epilogue; residual from the LDS self tile (bf16)
#pragma unroll
    for (int i = 0; i < 4; ++i) {
        const int lrow = lbase + quad * 4 + i;
        const int rr   = nbase + lrow;
        float res[4];
#pragma unroll
        for (int j = 0; j < 4; ++j)
            res[j] = bf2f(sSelf[lrow * SSTR + j * 16 + n16]);
        float o[4];
        if (MODE == 0) {
            float s4 = acc[0][i] + acc[1][i] + acc[2][i] + acc[3][i];
            s4 += __shfl_xor(s4, 1, 64);
            s4 += __shfl_xor(s4, 2, 64);
            s4 += __shfl_xor(s4, 4, 64);
            s4 += __shfl_xor(s4, 8, 64);
            float mu = s4 * (1.0f / 64.0f);
            float d0 = acc[0][i] - mu, d1 = acc[1][i] - mu,
                  d2 = acc[2][i] - mu, d3 = acc[3][i] - mu;
            float qq = d0 * d0 + d1 * d1 + d2 * d2 + d3 * d3;
            qq += __shfl_xor(qq, 1, 64);
            qq += __shfl_xor(qq, 2, 64);
            qq += __shfl_xor(qq, 4, 64);
            qq += __shfl_xor(qq, 8, 64);
            float rstd = rsqrtf(qq * (1.0f / 64.0f) + 1e-5f);
            o[0] = fmaxf(d0 * rstd * sg[ 0 + n16] + sb[ 0 + n16], 0.f) + res[0];
            o[1] = fmaxf(d1 * rstd * sg[16 + n16] + sb[16 + n16], 0.f) + res[1];
            o[2] = fmaxf(d2 * rstd * sg[32 + n16] + sb[32 + n16], 0.f) + res[2];
            o[3] = fmaxf(d3 * rstd * sg[48 + n16] + sb[48 + n16], 0.f) + res[3];
        } else {
            o[0] = acc[0][i] + res[0];
            o[1] = acc[1][i] + res[1];
            o[2] = acc[2][i] + res[2];
            o[3] = acc[3][i] + res[3];
            float qq = o[0] * o[0] + o[1] * o[1] + o[2] * o[2] + o[3] * o[3];
            qq += __shfl_xor(qq, 1, 64);
            qq += __shfl_xor(qq, 2, 64);
            qq += __shfl_xor(qq, 4, 64);
            qq += __shfl_xor(qq, 8, 64);
            float inv = 1.0f / fmaxf(sqrtf(qq), 1e-12f);
            o[0] *= inv; o[1] *= inv; o[2] *= inv; o[3] *= inv;
        }
        if (rr < N) {
#pragma unroll
            for (int j = 0; j < 4; ++j) {
                if (MODE == 0)
                    hbout[(size_t)rr * DD + j * 16 + n16] = f2bf_rne(o[j]);
                else
                    out[(size_t)rr * DD + j * 16 + n16] = o[j];
            }
        }
    }
}

// ===========================================================================
extern "C" void kernel_launch(void* const* d_in, const int* in_sizes, int n_in,
                              void* d_out, int out_size, void* d_ws, size_t ws_size,
                              hipStream_t stream) {
    const float* x   = (const float*)d_in[0];
    const int*   ei  = (const int*)d_in[1];   // [2, E] int32: row0 = src, row1 = dst
    const float* Wl0 = (const float*)d_in[2];
    const float* bl0 = (const float*)d_in[3];
    const float* Wr0 = (const float*)d_in[4];
    const float* Wl1 = (const float*)d_in[5];
    const float* bl1 = (const float*)d_in[6];
    const float* Wr1 = (const float*)d_in[7];
    const float* Wl2 = (const float*)d_in[8];
    const float* bl2 = (const float*)d_in[9];
    const float* Wr2 = (const float*)d_in[10];
    const float* g0  = (const float*)d_in[11];
    const float* b0  = (const float*)d_in[12];
    const float* g1  = (const float*)d_in[13];
    const float* b1  = (const float*)d_in[14];

    const int N = in_sizes[0] / DD;   // 100000
    const int E = in_sizes[1] / 2;    // 1250000
    const int* src = ei;
    const int* dst = ei + E;
    const int NB = (N + BNODES - 1) >> BSH;   // 196 buckets

    // Workspace: bucketBuf int2[256<<13] | HB0, HB1 bf16[N*64] | csr[E] |
    //            offsets[N+1] | gCnt[256] | wtg bf16[3*8192]  (~45.7 MB)
    int2* bucketBuf = (int2*)d_ws;
    unsigned short* HB0 = (unsigned short*)(bucketBuf + ((size_t)256 << BCAPSH));
    unsigned short* HB1 = HB0 + (size_t)N * DD;
    int*   csr     = (int*)(HB1 + (size_t)N * DD);
    int*   offsets = csr + E;
    int*   gCnt    = offsets + (N + 1);
    unsigned short* wtg =
        (unsigned short*)(((size_t)(gCnt + 256) + 15) & ~(size_t)15);
    float* out     = (float*)d_out;

    const int tiles = (N + 63) / 64;
    const int n4    = N * DD / 4;
    const int cgrid = (n4 + 255) / 256;
    const int bgrid = (E + 4095) / 4096;

    // ---- CSR build: bucket counting sort (graph static across layers)
    cvt_kernel<<<cgrid, 256, 0, stream>>>(x, HB0, n4, gCnt,
                                          Wl0, Wr0, Wl1, Wr1, Wl2, Wr2, wtg);
    bucket_kernel<<<bgrid, 1024, 0, stream>>>(src, dst, gCnt, bucketBuf, E);
    csr_build<<<NB, 512, 0, stream>>>(bucketBuf, gCnt, offsets, csr, N, E);

    // ---- 3 fused layers (bf16 ping-pong)
    sage_layer<0><<<tiles, 256, 0, stream>>>(HB0, offsets, csr, wtg,
                                             bl0, g0, b0, HB1, nullptr, N);
    sage_layer<0><<<tiles, 256, 0, stream>>>(HB1, offsets, csr, wtg + 8192,
                                             bl1, g1, b1, HB0, nullptr, N);
    sage_layer<1><<<tiles, 256, 0, stream>>>(HB0, offsets, csr, wtg + 16384,
                                             bl2, nullptr, nullptr, nullptr, out, N);
}

// Round 3
// 395.499 us; speedup vs baseline: 1.1314x; 1.0402x over previous
//
#include <hip/hip_runtime.h>

#define DD   64      // channels
#define SSTR 72      // LDS self/mean tile row stride (bf16 elems): 2-way only
#define BSH  9       // 512 nodes per bucket
#define BNODES 512
#define BCAPSH 13    // 8192 edges capacity per bucket (mean 6400 + 22 sigma)

typedef unsigned int uint32;
typedef __attribute__((ext_vector_type(8))) short short8;   // 8 bf16 (4 VGPRs)
typedef __attribute__((ext_vector_type(4))) float f32x4;    // MFMA accumulator

__device__ __forceinline__ unsigned short f2bf_rne(float f) {
    uint32 u = __float_as_uint(f);
    u += 0x7fffu + ((u >> 16) & 1u);   // round-to-nearest-even
    return (unsigned short)(u >> 16);
}
__device__ __forceinline__ float bf_lo(uint32 w) { return __uint_as_float(w << 16); }
__device__ __forceinline__ float bf_hi(uint32 w) { return __uint_as_float(w & 0xffff0000u); }
__device__ __forceinline__ float bf2f(unsigned short s) {
    return __uint_as_float(((uint32)s) << 16);
}

// ===========================================================================
// x (fp32) -> bf16 shadow; block 0 zeroes bucket counters; first 96 blocks
// also build the bf16 W^T tables for all 3 layers (wtg[layer][c*128+k],
// k<64 = Wl, k>=64 = Wr) so sage_layer needn't stage W in LDS.
// ===========================================================================
__global__ __launch_bounds__(256) void cvt_kernel(
    const float* __restrict__ x, unsigned short* __restrict__ xb, int n4,
    int* __restrict__ gCnt,
    const float* __restrict__ Wl0, const float* __restrict__ Wr0,
    const float* __restrict__ Wl1, const float* __restrict__ Wr1,
    const float* __restrict__ Wl2, const float* __restrict__ Wr2,
    unsigned short* __restrict__ wtg) {
    const int gid = blockIdx.x * 256 + threadIdx.x;
    if (blockIdx.x == 0) gCnt[threadIdx.x] = 0;
    if (gid < 3 * 2 * DD * DD) {              // 24576 W^T elements
        int layer = gid >> 13;
        int idx   = gid & 8191;
        int k = idx >> 6, c = idx & 63;
        const float* Wsrc;
        if (layer == 0)      Wsrc = (k < DD) ? Wl0 : Wr0;
        else if (layer == 1) Wsrc = (k < DD) ? Wl1 : Wr1;
        else                 Wsrc = (k < DD) ? Wl2 : Wr2;
        float v = Wsrc[(k & (DD - 1)) * DD + c];
        wtg[layer * 8192 + c * 128 + k] = f2bf_rne(v);
    }
    if (gid < n4) {
        float4 v = ((const float4*)x)[gid];
        ushort4 p;
        p.x = f2bf_rne(v.x); p.y = f2bf_rne(v.y);
        p.z = f2bf_rne(v.z); p.w = f2bf_rne(v.w);
        ((ushort4*)xb)[gid] = p;
    }
}

// ===========================================================================
// Pass 1: bucket edges by dst>>9 (LDS histogram, one global atomic per
// (block,bucket), scatter (src,dst) into fixed-capacity bucket regions).
// ===========================================================================
__global__ __launch_bounds__(1024) void bucket_kernel(const int* __restrict__ src,
                                                      const int* __restrict__ dst,
                                                      int* __restrict__ gCnt,
                                                      int2* __restrict__ buf, int E) {
    __shared__ int ldsCnt[256];
    __shared__ int base[256];
    const int t = threadIdx.x;
    if (t < 256) ldsCnt[t] = 0;
    __syncthreads();

    const int e0 = blockIdx.x * 4096;
    int bk[4], rk[4], sv[4], dv[4];
#pragma unroll
    for (int k = 0; k < 4; ++k) {
        int e = e0 + k * 1024 + t;
        bk[k] = -1;
        if (e < E) {
            dv[k] = dst[e];
            sv[k] = src[e];
            bk[k] = dv[k] >> BSH;
            rk[k] = atomicAdd(&ldsCnt[bk[k]], 1);
        }
    }
    __syncthreads();
    if (t < 256 && ldsCnt[t] > 0) base[t] = atomicAdd(&gCnt[t], ldsCnt[t]);
    __syncthreads();
#pragma unroll
    for (int k = 0; k < 4; ++k) {
        if (bk[k] >= 0) {
            int pos = (bk[k] << BCAPSH) + base[bk[k]] + rk[k];
            buf[pos] = make_int2(sv[k], dv[k]);
        }
    }
}

// ===========================================================================
// Pass 2: one block per bucket. Bucket base = masked wave reduction over
// gCnt (one scalar per block, no 256-scan). Degree scan = __shfl_up wave
// scans + 8-entry cross-wave combine. 4 barriers total (was ~36).
// ===========================================================================
__global__ __launch_bounds__(512) void csr_build(const int2* __restrict__ buf,
                                                 const int* __restrict__ gCnt,
                                                 int* __restrict__ offsets,
                                                 int* __restrict__ csr, int N, int E) {
    __shared__ int c1[BNODES];
    __shared__ int s2[BNODES];
    __shared__ int sw[16];
    const int b = blockIdx.x;
    const int t = threadIdx.x;
    const int lane = t & 63;
    const int w = t >> 6;

    // base = sum_{i<b} gCnt[i]  via masked butterfly reduction
    int gv = (t < 256 && t < b) ? gCnt[t] : 0;
#pragma unroll
    for (int d = 1; d < 64; d <<= 1) gv += __shfl_xor(gv, d, 64);
    if (lane == 0) sw[w] = gv;        // waves 4..7 contribute 0
    c1[t] = 0;
    __syncthreads();
    int base = 0;
#pragma unroll
    for (int i = 0; i < 8; ++i) base += sw[i];

    const int cnt = gCnt[b];
    const int2* bb = buf + ((size_t)b << BCAPSH);
    for (int i = t; i < cnt; i += 512) atomicAdd(&c1[bb[i].y & (BNODES - 1)], 1);
    __syncthreads();

    // inclusive scan of the 512 per-node counts: wave scan + cross-wave
    int v = c1[t];
    int x = v;
#pragma unroll
    for (int d = 1; d < 64; d <<= 1) {
        int y = __shfl_up(x, d, 64);
        if (lane >= d) x += y;
    }
    if (lane == 63) sw[8 + w] = x;
    __syncthreads();
    int woff = 0;
    for (int i = 0; i < w; ++i) woff += sw[8 + i];
    int excl = x + woff - v;

    const int node = (b << BSH) + t;
    if (node < N) offsets[node] = base + excl;
    if (b == 0 && t == 0) offsets[N] = E;

    s2[t] = excl;
    c1[t] = 0;
    __syncthreads();

    for (int i = t; i < cnt; i += 512) {
        int2 e = bb[i];
        int d = e.y & (BNODES - 1);
        int r = atomicAdd(&c1[d], 1);
        csr[base + s2[d] + r] = e.x;
    }
}

// ===========================================================================
// Fused SAGE layer (all-bf16 inter-layer state):
//   phase 1: stage self tile (LDS), gather neighbor means (8 lanes/node,
//            8-deep batches) -> LDS mean tile
//   phase 2: MFMA 16x16x32 [mean||self] @ [Wl;Wr] + bl, fp32 accum;
//            B-fragments from precomputed global bf16 W^T (16 KB,
//            L2-resident, shared by all blocks) -- no LDS staging. K-loop
//            unroll-1: only 4 W fragments in flight (16 VGPRs).
//   MODE 0: hbout = bf16(relu(LN(y)) + self);  MODE 1: out = l2norm(y + self)
// Block = 256 thr = 4 waves = 64 dst nodes. C/D: col=lane&15, row=quad*4+reg.
//
// Occupancy: LDS 19.2 KB -> 8 blocks/CU; VGPR must stay <=64 for 8
// waves/SIMD. __launch_bounds__(256,4) is the ONLY allocator mode that
// doesn't spill on this toolchain (min-waves 6 -> 40 VGPR and min-waves 8
// -> 32 VGPR both spilled v[8] to scratch, tripling HBM traffic; min-waves
// 4 historically allocates 52). The min-waves arg is a floor, not the
// residency mechanism -- hardware fills to the LDS/VGPR cap on its own.
// ===========================================================================
template <int MODE>
__global__ __launch_bounds__(256, 4) void sage_layer(
    const unsigned short* __restrict__ hbin,  // [N,64] bf16 layer input
    const int* __restrict__ offsets,          // [N+1]
    const int* __restrict__ csr,              // [E]
    const unsigned short* __restrict__ wt,    // [64][128] bf16 W^T this layer
    const float* __restrict__ bl,             // [64]
    const float* __restrict__ g,              // [64] LN gamma (MODE 0)
    const float* __restrict__ bta,            // [64] LN beta  (MODE 0)
    unsigned short* __restrict__ hbout,       // [N,64] bf16 (MODE 0)
    float* __restrict__ out,                  // [N,64] fp32 (MODE 1)
    int N) {
    __shared__ unsigned short sSelf[64 * SSTR]; // self rows bf16
    __shared__ unsigned short sMean[64 * SSTR]; // gathered means bf16
    __shared__ float sbl[DD], sg[DD], sb[DD];

    const int t = threadIdx.x;
    const int nbase = blockIdx.x * 64;

    if (t < DD) {
        sbl[t] = bl[t];
        if (MODE == 0) { sg[t] = g[t]; sb[t] = bta[t]; }
    }

    // ---- stage self tile: 64 rows x 8 uint4 chunks, coalesced
#pragma unroll
    for (int r = 0; r < 2; ++r) {
        int idx = r * 256 + t;
        int row = idx >> 3;
        int qq  = idx & 7;
        int n   = min(nbase + row, N - 1);
        uint4 v = ((const uint4*)(hbin + (size_t)n * DD))[qq];
        *(uint4*)(&sSelf[row * SSTR + qq * 8]) = v;
    }

    // ---- gather neighbor means: 32 groups x 8 lanes; 2 nodes per group
    {
        const int grp = t >> 3;
        const int q   = t & 7;           // 16 B chunk within 128 B row
#pragma unroll 1
        for (int rep = 0; rep < 2; ++rep) {
            int local = grp + rep * 32;
            int node  = nbase + local;
            float a0 = 0.f, a1 = 0.f, a2 = 0.f, a3 = 0.f,
                  a4 = 0.f, a5 = 0.f, a6 = 0.f, a7 = 0.f;
            int deg = 0;
            if (node < N) {
                int off0 = offsets[node];
                int off1 = offsets[node + 1];
                deg = off1 - off0;
                for (int j = off0; j < off1; j += 8) {
                    uint4 v[8];
#pragma unroll
                    for (int s = 0; s < 8; ++s) {
                        uint4 tt = make_uint4(0u, 0u, 0u, 0u);
                        int idx = j + s;
                        if (idx < off1) {
                            int sn = __builtin_nontemporal_load(&csr[idx]);
                            tt = ((const uint4*)(hbin + (size_t)sn * DD))[q];
                        }
                        v[s] = tt;
                    }
#pragma unroll
                    for (int s = 0; s < 8; ++s) {
                        a0 += bf_lo(v[s].x); a1 += bf_hi(v[s].x);
                        a2 += bf_lo(v[s].y); a3 += bf_hi(v[s].y);
                        a4 += bf_lo(v[s].z); a5 += bf_hi(v[s].z);
                        a6 += bf_lo(v[s].w); a7 += bf_hi(v[s].w);
                    }
                }
            }
            float invd = 1.0f / fmaxf((float)deg, 1.0f);
            ushort4 pa, pb;
            pa.x = f2bf_rne(a0 * invd); pa.y = f2bf_rne(a1 * invd);
            pa.z = f2bf_rne(a2 * invd); pa.w = f2bf_rne(a3 * invd);
            pb.x = f2bf_rne(a4 * invd); pb.y = f2bf_rne(a5 * invd);
            pb.z = f2bf_rne(a6 * invd); pb.w = f2bf_rne(a7 * invd);
            *(ushort4*)(&sMean[local * SSTR + q * 8])     = pa;
            *(ushort4*)(&sMean[local * SSTR + q * 8 + 4]) = pb;
        }
    }
    __syncthreads();

    // ---- MFMA phase: wave = 16 nodes x 64 cols
    const int wave = t >> 6;
    const int lane = t & 63;
    const int quad = lane >> 4;
    const int n16  = lane & 15;
    const int lbase = wave * 16;

    short8 af[4];
    af[0] = *(const short8*)(&sMean[(lbase + n16) * SSTR + quad * 8]);
    af[1] = *(const short8*)(&sMean[(lbase + n16) * SSTR + 32 + quad * 8]);
    af[2] = *(const short8*)(&sSelf[(lbase + n16) * SSTR + quad * 8]);
    af[3] = *(const short8*)(&sSelf[(lbase + n16) * SSTR + 32 + quad * 8]);

    f32x4 acc[4];
#pragma unroll
    for (int j = 0; j < 4; ++j) {
        float bv = sbl[j * 16 + n16];
        acc[j] = (f32x4){bv, bv, bv, bv};
    }
#pragma unroll 1
    for (int s = 0; s < 4; ++s) {
#pragma unroll
        for (int j = 0; j < 4; ++j) {
            short8 bf = *(const short8*)(wt + (j * 16 + n16) * 128 + s * 32 + quad * 8);
            acc[j] = __builtin_amdgcn_mfma_f32_16x16x32_bf16(af[s], bf, acc[j], 0, 0, 0);
        }
    }

    // ---- epilogue; residual from the LDS self tile (bf16)
#pragma unroll
    for (int i = 0; i < 4; ++i) {
        const int lrow = lbase + quad * 4 + i;
        const int rr   = nbase + lrow;
        float res[4];
#pragma unroll
        for (int j = 0; j < 4; ++j)
            res[j] = bf2f(sSelf[lrow * SSTR + j * 16 + n16]);
        float o[4];
        if (MODE == 0) {
            float s4 = acc[0][i] + acc[1][i] + acc[2][i] + acc[3][i];
            s4 += __shfl_xor(s4, 1, 64);
            s4 += __shfl_xor(s4, 2, 64);
            s4 += __shfl_xor(s4, 4, 64);
            s4 += __shfl_xor(s4, 8, 64);
            float mu = s4 * (1.0f / 64.0f);
            float d0 = acc[0][i] - mu, d1 = acc[1][i] - mu,
                  d2 = acc[2][i] - mu, d3 = acc[3][i] - mu;
            float qq = d0 * d0 + d1 * d1 + d2 * d2 + d3 * d3;
            qq += __shfl_xor(qq, 1, 64);
            qq += __shfl_xor(qq, 2, 64);
            qq += __shfl_xor(qq, 4, 64);
            qq += __shfl_xor(qq, 8, 64);
            float rstd = rsqrtf(qq * (1.0f / 64.0f) + 1e-5f);
            o[0] = fmaxf(d0 * rstd * sg[ 0 + n16] + sb[ 0 + n16], 0.f) + res[0];
            o[1] = fmaxf(d1 * rstd * sg[16 + n16] + sb[16 + n16], 0.f) + res[1];
            o[2] = fmaxf(d2 * rstd * sg[32 + n16] + sb[32 + n16], 0.f) + res[2];
            o[3] = fmaxf(d3 * rstd * sg[48 + n16] + sb[48 + n16], 0.f) + res[3];
        } else {
            o[0] = acc[0][i] + res[0];
            o[1] = acc[1][i] + res[1];
            o[2] = acc[2][i] + res[2];
            o[3] = acc[3][i] + res[3];
            float qq = o[0] * o[0] + o[1] * o[1] + o[2] * o[2] + o[3] * o[3];
            qq += __shfl_xor(qq, 1, 64);
            qq += __shfl_xor(qq, 2, 64);
            qq += __shfl_xor(qq, 4, 64);
            qq += __shfl_xor(qq, 8, 64);
            float inv = 1.0f / fmaxf(sqrtf(qq), 1e-12f);
            o[0] *= inv; o[1] *= inv; o[2] *= inv; o[3] *= inv;
        }
        if (rr < N) {
#pragma unroll
            for (int j = 0; j < 4; ++j) {
                if (MODE == 0)
                    hbout[(size_t)rr * DD + j * 16 + n16] = f2bf_rne(o[j]);
                else
                    out[(size_t)rr * DD + j * 16 + n16] = o[j];
            }
        }
    }
}

// ===========================================================================
extern "C" void kernel_launch(void* const* d_in, const int* in_sizes, int n_in,
                              void* d_out, int out_size, void* d_ws, size_t ws_size,
                              hipStream_t stream) {
    const float* x   = (const float*)d_in[0];
    const int*   ei  = (const int*)d_in[1];   // [2, E] int32: row0 = src, row1 = dst
    const float* Wl0 = (const float*)d_in[2];
    const float* bl0 = (const float*)d_in[3];
    const float* Wr0 = (const float*)d_in[4];
    const float* Wl1 = (const float*)d_in[5];
    const float* bl1 = (const float*)d_in[6];
    const float* Wr1 = (const float*)d_in[7];
    const float* Wl2 = (const float*)d_in[8];
    const float* bl2 = (const float*)d_in[9];
    const float* Wr2 = (const float*)d_in[10];
    const float* g0  = (const float*)d_in[11];
    const float* b0  = (const float*)d_in[12];
    const float* g1  = (const float*)d_in[13];
    const float* b1  = (const float*)d_in[14];

    const int N = in_sizes[0] / DD;   // 100000
    const int E = in_sizes[1] / 2;    // 1250000
    const int* src = ei;
    const int* dst = ei + E;
    const int NB = (N + BNODES - 1) >> BSH;   // 196 buckets

    // Workspace: bucketBuf int2[256<<13] | HB0, HB1 bf16[N*64] | csr[E] |
    //            offsets[N+1] | gCnt[256] | wtg bf16[3*8192]  (~45.7 MB)
    int2* bucketBuf = (int2*)d_ws;
    unsigned short* HB0 = (unsigned short*)(bucketBuf + ((size_t)256 << BCAPSH));
    unsigned short* HB1 = HB0 + (size_t)N * DD;
    int*   csr     = (int*)(HB1 + (size_t)N * DD);
    int*   offsets = csr + E;
    int*   gCnt    = offsets + (N + 1);
    unsigned short* wtg =
        (unsigned short*)(((size_t)(gCnt + 256) + 15) & ~(size_t)15);
    float* out     = (float*)d_out;

    const int tiles = (N + 63) / 64;
    const int n4    = N * DD / 4;
    const int cgrid = (n4 + 255) / 256;
    const int bgrid = (E + 4095) / 4096;

    // ---- CSR build: bucket counting sort (graph static across layers)
    cvt_kernel<<<cgrid, 256, 0, stream>>>(x, HB0, n4, gCnt,
                                          Wl0, Wr0, Wl1, Wr1, Wl2, Wr2, wtg);
    bucket_kernel<<<bgrid, 1024, 0, stream>>>(src, dst, gCnt, bucketBuf, E);
    csr_build<<<NB, 512, 0, stream>>>(bucketBuf, gCnt, offsets, csr, N, E);

    // ---- 3 fused layers (bf16 ping-pong)
    sage_layer<0><<<tiles, 256, 0, stream>>>(HB0, offsets, csr, wtg,
                                             bl0, g0, b0, HB1, nullptr, N);
    sage_layer<0><<<tiles, 256, 0, stream>>>(HB1, offsets, csr, wtg + 8192,
                                             bl1, g1, b1, HB0, nullptr, N);
    sage_layer<1><<<tiles, 256, 0, stream>>>(HB0, offsets, csr, wtg + 16384,
                                             bl2, nullptr, nullptr, nullptr, out, N);
}

// Round 4
// 306.483 us; speedup vs baseline: 1.4601x; 1.2904x over previous
//
#include <hip/hip_runtime.h>

#define DD   64      // channels
#define BSH  9       // 512 nodes per bucket
#define BNODES 512
#define BCAPSH 13    // 8192 edges capacity per bucket (mean 6400 + 22 sigma)

typedef unsigned int uint32;
typedef __attribute__((ext_vector_type(8))) short short8;   // 8 bf16 (4 VGPRs)
typedef __attribute__((ext_vector_type(4))) float f32x4;    // MFMA accumulator

__device__ __forceinline__ unsigned short f2bf_rne(float f) {
    uint32 u = __float_as_uint(f);
    u += 0x7fffu + ((u >> 16) & 1u);   // round-to-nearest-even
    return (unsigned short)(u >> 16);
}
__device__ __forceinline__ float bf_lo(uint32 w) { return __uint_as_float(w << 16); }
__device__ __forceinline__ float bf_hi(uint32 w) { return __uint_as_float(w & 0xffff0000u); }
__device__ __forceinline__ float bf2f(unsigned short s) {
    return __uint_as_float(((uint32)s) << 16);
}

// ===========================================================================
// x (fp32) -> bf16 shadow; block 0 zeroes bucket counters; first 96 blocks
// also build the bf16 W^T tables for all 3 layers (wtg[layer][c*128+k],
// k<64 = Wl, k>=64 = Wr). Layout validated in round 3 (passed).
// ===========================================================================
__global__ __launch_bounds__(256) void cvt_kernel(
    const float* __restrict__ x, unsigned short* __restrict__ xb, int n4,
    int* __restrict__ gCnt,
    const float* __restrict__ Wl0, const float* __restrict__ Wr0,
    const float* __restrict__ Wl1, const float* __restrict__ Wr1,
    const float* __restrict__ Wl2, const float* __restrict__ Wr2,
    unsigned short* __restrict__ wtg) {
    const int gid = blockIdx.x * 256 + threadIdx.x;
    if (blockIdx.x == 0) gCnt[threadIdx.x] = 0;
    if (gid < 3 * 2 * DD * DD) {              // 24576 W^T elements
        int layer = gid >> 13;
        int idx   = gid & 8191;
        int k = idx >> 6, c = idx & 63;
        const float* Wsrc;
        if (layer == 0)      Wsrc = (k < DD) ? Wl0 : Wr0;
        else if (layer == 1) Wsrc = (k < DD) ? Wl1 : Wr1;
        else                 Wsrc = (k < DD) ? Wl2 : Wr2;
        float v = Wsrc[(k & (DD - 1)) * DD + c];
        wtg[layer * 8192 + c * 128 + k] = f2bf_rne(v);
    }
    if (gid < n4) {
        float4 v = ((const float4*)x)[gid];
        ushort4 p;
        p.x = f2bf_rne(v.x); p.y = f2bf_rne(v.y);
        p.z = f2bf_rne(v.z); p.w = f2bf_rne(v.w);
        ((ushort4*)xb)[gid] = p;
    }
}

// ===========================================================================
// Pass 1: bucket edges by dst>>9 (LDS histogram, one global atomic per
// (block,bucket), scatter (src,dst) into fixed-capacity bucket regions).
// ===========================================================================
__global__ __launch_bounds__(1024) void bucket_kernel(const int* __restrict__ src,
                                                      const int* __restrict__ dst,
                                                      int* __restrict__ gCnt,
                                                      int2* __restrict__ buf, int E) {
    __shared__ int ldsCnt[256];
    __shared__ int base[256];
    const int t = threadIdx.x;
    if (t < 256) ldsCnt[t] = 0;
    __syncthreads();

    const int e0 = blockIdx.x * 4096;
    int bk[4], rk[4], sv[4], dv[4];
#pragma unroll
    for (int k = 0; k < 4; ++k) {
        int e = e0 + k * 1024 + t;
        bk[k] = -1;
        if (e < E) {
            dv[k] = dst[e];
            sv[k] = src[e];
            bk[k] = dv[k] >> BSH;
            rk[k] = atomicAdd(&ldsCnt[bk[k]], 1);
        }
    }
    __syncthreads();
    if (t < 256 && ldsCnt[t] > 0) base[t] = atomicAdd(&gCnt[t], ldsCnt[t]);
    __syncthreads();
#pragma unroll
    for (int k = 0; k < 4; ++k) {
        if (bk[k] >= 0) {
            int pos = (bk[k] << BCAPSH) + base[bk[k]] + rk[k];
            buf[pos] = make_int2(sv[k], dv[k]);
        }
    }
}

// ===========================================================================
// Pass 2: one block per bucket. Bucket base = masked wave reduction over
// gCnt; degree scan = __shfl_up wave scans + cross-wave combine.
// ===========================================================================
__global__ __launch_bounds__(512) void csr_build(const int2* __restrict__ buf,
                                                 const int* __restrict__ gCnt,
                                                 int* __restrict__ offsets,
                                                 int* __restrict__ csr, int N, int E) {
    __shared__ int c1[BNODES];
    __shared__ int s2[BNODES];
    __shared__ int sw[16];
    const int b = blockIdx.x;
    const int t = threadIdx.x;
    const int lane = t & 63;
    const int w = t >> 6;

    // base = sum_{i<b} gCnt[i]  via masked butterfly reduction
    int gv = (t < 256 && t < b) ? gCnt[t] : 0;
#pragma unroll
    for (int d = 1; d < 64; d <<= 1) gv += __shfl_xor(gv, d, 64);
    if (lane == 0) sw[w] = gv;        // waves 4..7 contribute 0
    c1[t] = 0;
    __syncthreads();
    int base = 0;
#pragma unroll
    for (int i = 0; i < 8; ++i) base += sw[i];

    const int cnt = gCnt[b];
    const int2* bb = buf + ((size_t)b << BCAPSH);
    for (int i = t; i < cnt; i += 512) atomicAdd(&c1[bb[i].y & (BNODES - 1)], 1);
    __syncthreads();

    // inclusive scan of the 512 per-node counts: wave scan + cross-wave
    int v = c1[t];
    int x = v;
#pragma unroll
    for (int d = 1; d < 64; d <<= 1) {
        int y = __shfl_up(x, d, 64);
        if (lane >= d) x += y;
    }
    if (lane == 63) sw[8 + w] = x;
    __syncthreads();
    int woff = 0;
    for (int i = 0; i < w; ++i) woff += sw[8 + i];
    int excl = x + woff - v;

    const int node = (b << BSH) + t;
    if (node < N) offsets[node] = base + excl;
    if (b == 0 && t == 0) offsets[N] = E;

    s2[t] = excl;
    c1[t] = 0;
    __syncthreads();

    for (int i = t; i < cnt; i += 512) {
        int2 e = bb[i];
        int d = e.y & (BNODES - 1);
        int r = atomicAdd(&c1[d], 1);
        csr[base + s2[d] + r] = e.x;
    }
}

// ===========================================================================
// Gather kernel: pure neighbor-mean. 8 lanes/node, 8-deep load batches,
// ZERO LDS, no MFMA, no epilogue state -> live set ~50 VGPR at the proven
// (256,4) allocator mode -> <=64 VGPR -> 8 waves/SIMD (32/CU, 2x the fused
// kernel) AND the full 8-deep batch stays in registers (rounds 1-3 showed
// perf is monotone in per-wave MLP: VGPR 52/44/40 -> 62.7/90/97 us).
// Writes bf16 mean rows (same rounding as the old LDS path -> numerics id).
// ===========================================================================
__global__ __launch_bounds__(256, 4) void gather_mean(
    const unsigned short* __restrict__ hbin,  // [N,64] bf16 layer input
    const int* __restrict__ offsets,          // [N+1]
    const int* __restrict__ csr,              // [E]
    unsigned short* __restrict__ mean,        // [N,64] bf16 out
    int N) {
    const int grp  = threadIdx.x >> 3;        // 0..31: node within block
    const int q    = threadIdx.x & 7;         // 16 B chunk within 128 B row
    const int node = blockIdx.x * 32 + grp;
    if (node >= N) return;

    const int off0 = offsets[node];
    const int off1 = offsets[node + 1];
    const int deg  = off1 - off0;

    float a0 = 0.f, a1 = 0.f, a2 = 0.f, a3 = 0.f,
          a4 = 0.f, a5 = 0.f, a6 = 0.f, a7 = 0.f;
#pragma unroll 1
    for (int j = off0; j < off1; j += 8) {
        uint4 v[8];
#pragma unroll
        for (int s = 0; s < 8; ++s) {
            uint4 tt = make_uint4(0u, 0u, 0u, 0u);
            int idx = j + s;
            if (idx < off1) {
                int sn = __builtin_nontemporal_load(&csr[idx]);
                tt = ((const uint4*)(hbin + (size_t)sn * DD))[q];
            }
            v[s] = tt;
        }
#pragma unroll
        for (int s = 0; s < 8; ++s) {
            a0 += bf_lo(v[s].x); a1 += bf_hi(v[s].x);
            a2 += bf_lo(v[s].y); a3 += bf_hi(v[s].y);
            a4 += bf_lo(v[s].z); a5 += bf_hi(v[s].z);
            a6 += bf_lo(v[s].w); a7 += bf_hi(v[s].w);
        }
    }
    float invd = 1.0f / fmaxf((float)deg, 1.0f);
    uint4 wv;
    wv.x = (uint32)f2bf_rne(a0 * invd) | ((uint32)f2bf_rne(a1 * invd) << 16);
    wv.y = (uint32)f2bf_rne(a2 * invd) | ((uint32)f2bf_rne(a3 * invd) << 16);
    wv.z = (uint32)f2bf_rne(a4 * invd) | ((uint32)f2bf_rne(a5 * invd) << 16);
    wv.w = (uint32)f2bf_rne(a6 * invd) | ((uint32)f2bf_rne(a7 * invd) << 16);
    *(uint4*)(mean + (size_t)node * DD + q * 8) = wv;   // coalesced 128 B/node
}

// ===========================================================================
// Transform kernel: y = [mean||self] @ [Wl;Wr] + bl, then
//   MODE 0: hbout = bf16(relu(LN(y)) + self);  MODE 1: out = l2norm(y+self).
// Dense + streaming: A-fragments read straight from global mean/self rows
// (coalesced 16 B/lane within a 2 KB window); B-fragments from the global
// bf16 W^T table (16 KB, L1/L2-resident, validated round 3); bias/gamma/
// beta via broadcast loads. ZERO LDS, ZERO barriers. ~110 VGPR < 128 cap.
// Block = 256 thr = 4 waves = 64 nodes. C/D: col=lane&15, row=quad*4+reg.
// ===========================================================================
template <int MODE>
__global__ __launch_bounds__(256, 4) void sage_xform(
    const unsigned short* __restrict__ hbin,  // [N,64] bf16 self
    const unsigned short* __restrict__ mean,  // [N,64] bf16 neighbor mean
    const unsigned short* __restrict__ wt,    // [64][128] bf16 W^T this layer
    const float* __restrict__ bl,             // [64]
    const float* __restrict__ g,              // [64] LN gamma (MODE 0)
    const float* __restrict__ bta,            // [64] LN beta  (MODE 0)
    unsigned short* __restrict__ hbout,       // [N,64] bf16 (MODE 0)
    float* __restrict__ out,                  // [N,64] fp32 (MODE 1)
    int N) {
    const int t = threadIdx.x;
    const int nbase = blockIdx.x * 64;
    const int wave = t >> 6;
    const int lane = t & 63;
    const int quad = lane >> 4;
    const int n16  = lane & 15;
    const int lbase = wave * 16;

    const int arow = min(nbase + lbase + n16, N - 1);   // clamp tail rows
    short8 af[4];
    af[0] = *(const short8*)(mean + (size_t)arow * DD + quad * 8);
    af[1] = *(const short8*)(mean + (size_t)arow * DD + 32 + quad * 8);
    af[2] = *(const short8*)(hbin + (size_t)arow * DD + quad * 8);
    af[3] = *(const short8*)(hbin + (size_t)arow * DD + 32 + quad * 8);

    f32x4 acc[4];
#pragma unroll
    for (int j = 0; j < 4; ++j) {
        float bv = bl[j * 16 + n16];
        acc[j] = (f32x4){bv, bv, bv, bv};
    }
#pragma unroll
    for (int s = 0; s < 4; ++s) {
#pragma unroll
        for (int j = 0; j < 4; ++j) {
            short8 bf = *(const short8*)(wt + (j * 16 + n16) * 128 + s * 32 + quad * 8);
            acc[j] = __builtin_amdgcn_mfma_f32_16x16x32_bf16(af[s], bf, acc[j], 0, 0, 0);
        }
    }

    float sg[4], sb[4];
    if (MODE == 0) {
#pragma unroll
        for (int j = 0; j < 4; ++j) { sg[j] = g[j * 16 + n16]; sb[j] = bta[j * 16 + n16]; }
    }

#pragma unroll
    for (int i = 0; i < 4; ++i) {
        const int lrow = lbase + quad * 4 + i;
        const int rr   = nbase + lrow;
        const int rrc  = min(rr, N - 1);
        float res[4];
#pragma unroll
        for (int j = 0; j < 4; ++j)
            res[j] = bf2f(hbin[(size_t)rrc * DD + j * 16 + n16]);
        float o[4];
        if (MODE == 0) {
            float s4 = acc[0][i] + acc[1][i] + acc[2][i] + acc[3][i];
            s4 += __shfl_xor(s4, 1, 64);
            s4 += __shfl_xor(s4, 2, 64);
            s4 += __shfl_xor(s4, 4, 64);
            s4 += __shfl_xor(s4, 8, 64);
            float mu = s4 * (1.0f / 64.0f);
            float d0 = acc[0][i] - mu, d1 = acc[1][i] - mu,
                  d2 = acc[2][i] - mu, d3 = acc[3][i] - mu;
            float qq = d0 * d0 + d1 * d1 + d2 * d2 + d3 * d3;
            qq += __shfl_xor(qq, 1, 64);
            qq += __shfl_xor(qq, 2, 64);
            qq += __shfl_xor(qq, 4, 64);
            qq += __shfl_xor(qq, 8, 64);
            float rstd = rsqrtf(qq * (1.0f / 64.0f) + 1e-5f);
            o[0] = fmaxf(d0 * rstd * sg[0] + sb[0], 0.f) + res[0];
            o[1] = fmaxf(d1 * rstd * sg[1] + sb[1], 0.f) + res[1];
            o[2] = fmaxf(d2 * rstd * sg[2] + sb[2], 0.f) + res[2];
            o[3] = fmaxf(d3 * rstd * sg[3] + sb[3], 0.f) + res[3];
        } else {
            o[0] = acc[0][i] + res[0];
            o[1] = acc[1][i] + res[1];
            o[2] = acc[2][i] + res[2];
            o[3] = acc[3][i] + res[3];
            float qq = o[0] * o[0] + o[1] * o[1] + o[2] * o[2] + o[3] * o[3];
            qq += __shfl_xor(qq, 1, 64);
            qq += __shfl_xor(qq, 2, 64);
            qq += __shfl_xor(qq, 4, 64);
            qq += __shfl_xor(qq, 8, 64);
            float inv = 1.0f / fmaxf(sqrtf(qq), 1e-12f);
            o[0] *= inv; o[1] *= inv; o[2] *= inv; o[3] *= inv;
        }
        if (rr < N) {
#pragma unroll
            for (int j = 0; j < 4; ++j) {
                if (MODE == 0)
                    hbout[(size_t)rr * DD + j * 16 + n16] = f2bf_rne(o[j]);
                else
                    out[(size_t)rr * DD + j * 16 + n16] = o[j];
            }
        }
    }
}

// ===========================================================================
extern "C" void kernel_launch(void* const* d_in, const int* in_sizes, int n_in,
                              void* d_out, int out_size, void* d_ws, size_t ws_size,
                              hipStream_t stream) {
    const float* x   = (const float*)d_in[0];
    const int*   ei  = (const int*)d_in[1];   // [2, E] int32: row0 = src, row1 = dst
    const float* Wl0 = (const float*)d_in[2];
    const float* bl0 = (const float*)d_in[3];
    const float* Wr0 = (const float*)d_in[4];
    const float* Wl1 = (const float*)d_in[5];
    const float* bl1 = (const float*)d_in[6];
    const float* Wr1 = (const float*)d_in[7];
    const float* Wl2 = (const float*)d_in[8];
    const float* bl2 = (const float*)d_in[9];
    const float* Wr2 = (const float*)d_in[10];
    const float* g0  = (const float*)d_in[11];
    const float* b0  = (const float*)d_in[12];
    const float* g1  = (const float*)d_in[13];
    const float* b1  = (const float*)d_in[14];

    const int N = in_sizes[0] / DD;   // 100000
    const int E = in_sizes[1] / 2;    // 1250000
    const int* src = ei;
    const int* dst = ei + E;
    const int NB = (N + BNODES - 1) >> BSH;   // 196 buckets

    // Workspace: bucketBuf int2[256<<13] | HB0, HB1, MEAN bf16[N*64] |
    //            csr[E] | offsets[N+1] | gCnt[256] | wtg bf16[3*8192]
    int2* bucketBuf = (int2*)d_ws;
    unsigned short* HB0  = (unsigned short*)(bucketBuf + ((size_t)256 << BCAPSH));
    unsigned short* HB1  = HB0 + (size_t)N * DD;
    unsigned short* MEAN = HB1 + (size_t)N * DD;
    int*   csr     = (int*)(MEAN + (size_t)N * DD);
    int*   offsets = csr + E;
    int*   gCnt    = offsets + (N + 1);
    unsigned short* wtg =
        (unsigned short*)(((size_t)(gCnt + 256) + 15) & ~(size_t)15);
    float* out     = (float*)d_out;

    const int tiles  = (N + 63) / 64;         // xform grid
    const int ggrid  = (N + 31) / 32;         // gather grid
    const int n4     = N * DD / 4;
    const int cgrid  = (n4 + 255) / 256;
    const int bgrid  = (E + 4095) / 4096;

    // ---- CSR build: bucket counting sort (graph static across layers)
    cvt_kernel<<<cgrid, 256, 0, stream>>>(x, HB0, n4, gCnt,
                                          Wl0, Wr0, Wl1, Wr1, Wl2, Wr2, wtg);
    bucket_kernel<<<bgrid, 1024, 0, stream>>>(src, dst, gCnt, bucketBuf, E);
    csr_build<<<NB, 512, 0, stream>>>(bucketBuf, gCnt, offsets, csr, N, E);

    // ---- 3 layers: gather (latency-optimized) + transform (dense streaming)
    gather_mean<<<ggrid, 256, 0, stream>>>(HB0, offsets, csr, MEAN, N);
    sage_xform<0><<<tiles, 256, 0, stream>>>(HB0, MEAN, wtg,
                                             bl0, g0, b0, HB1, nullptr, N);
    gather_mean<<<ggrid, 256, 0, stream>>>(HB1, offsets, csr, MEAN, N);
    sage_xform<0><<<tiles, 256, 0, stream>>>(HB1, MEAN, wtg + 8192,
                                             bl1, g1, b1, HB0, nullptr, N);
    gather_mean<<<ggrid, 256, 0, stream>>>(HB0, offsets, csr, MEAN, N);
    sage_xform<1><<<tiles, 256, 0, stream>>>(HB0, MEAN, wtg + 16384,
                                             bl2, nullptr, nullptr, nullptr, out, N);
}